// Round 11
// baseline (425.185 us; speedup 1.0000x reference)
//
#include <hip/hip_runtime.h>
#include <cstdint>
#include <cstddef>

// ---------------------------------------------------------------------------
// TransformConvCrossAttention: B=4, SQ=SK=2048, D=1024, Kconv=3
// fp16 compute, fp32 MFMA accumulation; fp32 in/out (runtime-verified).
// R11: projections read fp32 A directly (AFP32 GEMM path, in-register cvt
//      after LDS) -> k_h_to_f16 (201MB pass) deleted; kv-proj MTILE=64 NT=16
//      (2048 blocks); prep merged (w-convert + mask-pack + conv-params).
//      mask8 lives AFTER the flags page (w16 slots stay intact for the
//      projections). 11 dispatches.
// ---------------------------------------------------------------------------

#define GLOBAL_AS __attribute__((address_space(1)))
#define LDS_AS    __attribute__((address_space(3)))

typedef _Float16 h8 __attribute__((ext_vector_type(8)));
typedef float    f4_t __attribute__((ext_vector_type(4)));
typedef unsigned short us8 __attribute__((ext_vector_type(8)));

__device__ __forceinline__ float bf2f(unsigned short u) {
    union { unsigned int i; float f; } x; x.i = ((unsigned int)u) << 16; return x.f;
}
__device__ __forceinline__ float rd(const void* p, long i, int isBf) {
    return isBf ? bf2f(((const unsigned short*)p)[i]) : ((const float*)p)[i];
}

// ---------------------------------------------------------------------------
struct Probe16 { const unsigned short* p[16]; int n[16]; };

__global__ void k_probes(Probe16 a, const unsigned int* __restrict__ mask,
                         int* __restrict__ flags) {
    if (blockIdx.x < 16) {
        __shared__ int cnt;
        if (threadIdx.x == 0) cnt = 0;
        __syncthreads();
        const unsigned short* s = a.p[blockIdx.x];
        const int n = a.n[blockIdx.x];
        int bad = 0;
        for (int i = threadIdx.x; i < n; i += 256) {
            int e = (s[i] >> 7) & 0xFF;
            if (e >= 0x8F || (e > 0 && e <= 0x60)) bad++;
        }
        atomicAdd(&cnt, bad);
        __syncthreads();
        if (threadIdx.x == 0) flags[blockIdx.x] = (cnt * 4 > n) ? 0 : 1;
    } else {
        __shared__ int vi32, vf32, vbf, vf16;
        if (threadIdx.x == 0) { vi32 = vf32 = vbf = vf16 = 0; }
        __syncthreads();
        int bi32 = 0, bf32 = 0, bbf = 0, bf16c = 0;
        for (int i = threadIdx.x; i < 4096; i += 256) {
            unsigned int w = mask[i];
            if (!(w == 0u || w == 1u)) bi32++;
            if (!(w == 0u || w == 0x3F800000u)) bf32++;
            unsigned int h0 = w & 0xFFFFu, h1 = w >> 16;
            if (!((h0 == 0u || h0 == 0x3F80u) && (h1 == 0u || h1 == 0x3F80u))) bbf++;
            if (!((h0 == 0u || h0 == 0x3C00u) && (h1 == 0u || h1 == 0x3C00u))) bf16c++;
        }
        if (bi32) atomicAdd(&vi32, 1);
        if (bf32) atomicAdd(&vf32, 1);
        if (bbf)  atomicAdd(&vbf, 1);
        if (bf16c) atomicAdd(&vf16, 1);
        __syncthreads();
        if (threadIdx.x == 0) {
            int w;
            if (vi32 == 0) w = 4;
            else if (vf32 == 0) w = 4;
            else if (vbf == 0) w = 2;
            else if (vf16 == 0) w = 2;
            else w = 1;
            flags[16] = w;
        }
    }
}

// ---------------------------------------------------------------------------
__device__ __forceinline__ h8 cvt8(const void* src, size_t off8, int isBf) {
    h8 d;
    if (isBf) {
        us8 s = *(const us8*)((const unsigned short*)src + off8 * 8);
#pragma unroll
        for (int u = 0; u < 8; ++u) d[u] = (_Float16)bf2f(s[u]);
    } else {
        const float* f = (const float*)src + off8 * 8;
        f4_t a = *(const f4_t*)f;
        f4_t b = *(const f4_t*)(f + 4);
#pragma unroll
        for (int u = 0; u < 4; ++u) { d[u] = (_Float16)a[u]; d[4 + u] = (_Float16)b[u]; }
    }
    return d;
}

// ---------------------------------------------------------------------------
// Merged prep: blocks [0,2048) convert 4 weight matrices to fp16;
// [2048,6144) pack mask to bytes (into mout, NOT overlapping w16);
// block 6144 builds planar conv params + tanh(gate).
struct Ptr4 { const void* p[4]; };
struct ConvSrc { const void* kern[3]; const void* cb[3]; const void* gate[3]; };

__global__ void k_prep(Ptr4 wsrc, _Float16* __restrict__ wdst, int nW8,
                       const void* __restrict__ m, unsigned char* __restrict__ mout,
                       long nM, ConvSrc cp, _Float16* __restrict__ par,
                       float* __restrict__ tg, int D,
                       const int* __restrict__ flags) {
    const long id = blockIdx.x;
    if (id < 2048) {
        int i = (int)id * 256 + threadIdx.x;
        if (i >= 4 * nW8) return;
        int seg = i / nW8, off = i - seg * nW8;
        h8 d = cvt8(wsrc.p[seg], off, flags[2 + seg]);
        *(h8*)(wdst + (size_t)i * 8) = d;
    } else if (id < 6144) {
        long i = ((id - 2048) * 256 + threadIdx.x) * 4;
        if (i >= nM) return;
        const int w = flags[16];
        unsigned int packed = 0;
        if (w == 4) {
            const unsigned int* p = (const unsigned int*)m;
#pragma unroll
            for (int u = 0; u < 4; ++u) packed |= (p[i + u] != 0u ? 1u : 0u) << (8 * u);
        } else if (w == 2) {
            const unsigned short* p = (const unsigned short*)m;
#pragma unroll
            for (int u = 0; u < 4; ++u) packed |= (p[i + u] != 0u ? 1u : 0u) << (8 * u);
        } else {
            const unsigned char* p = (const unsigned char*)m;
#pragma unroll
            for (int u = 0; u < 4; ++u) packed |= (p[i + u] != 0u ? 1u : 0u) << (8 * u);
        }
        *(unsigned int*)(mout + i) = packed;
    } else {
#pragma unroll
        for (int t = 0; t < 3; ++t) {
            const int kIs = flags[6 + t], cIs = flags[13 + t];
            for (int d = threadIdx.x; d < D; d += 256) {
#pragma unroll
                for (int j = 0; j < 3; ++j)
                    par[t * 3 * D + j * D + d] = (_Float16)rd(cp.kern[t], (long)d * 3 + j, kIs);
                par[9 * D + t * D + d] = (_Float16)rd(cp.cb[t], d, cIs);
            }
        }
        if (threadIdx.x < 3) {
            const void* g = cp.gate[threadIdx.x];
            float gv = rd(g, 0, ((const unsigned int*)g)[0] == 0u ? 1 : 0);
            tg[threadIdx.x] = tanhf(gv);
        }
    }
}

// ---------------------------------------------------------------------------
// NT GEMM, MTILE x 128 x BK=64, 4 waves/block. AFP32: A is fp32 in
// global+LDS, converted to fp16 in-register after the LDS read (v_cvt RNE).
// Seg swizzle p=(seg+row)&(SEG-1): fragment reads hit 8 start banks x 2
// lanes/phase (conflict-free family, measured 0). XCD-aware 1D decode.
template <int MODE, int MTILE, int AFP32>
__global__ __launch_bounds__(256, 4) void k_gemm_nt(
    const void* __restrict__ A, const _Float16* __restrict__ Bm,
    void* __restrict__ Cout,
    const void* __restrict__ bias, const int* __restrict__ biasFlag,
    const void* __restrict__ bias2, const int* __restrict__ biasFlag2,
    int N, int K, long sA, long sB, long sC,
    float scale, const unsigned char* __restrict__ mask8,
    int NT, int BZ) {

    constexpr int NI  = (MTILE == 128) ? 4 : 2;
    constexpr int ES  = AFP32 ? 4 : 2;
    constexpr int SEG = 4 * ES;                  // 16B segs per A row
    constexpr int CHA = MTILE * SEG / 256;       // A chunks per thread
    __shared__ __align__(16) char AsRaw[(size_t)MTILE * 64 * ES];
    __shared__ __align__(16) _Float16 Bs[128 * 64];
    _Float16* As16 = (_Float16*)AsRaw;
    float*    As32 = (float*)AsRaw;

    const long id = blockIdx.x;
    const int xcd = (int)(id & 7);
    const long local = id >> 3;
    const int col = (int)(local % NT);
    const long g = (local / NT) * 8 + xcd;
    const int bz = (int)(g % BZ);
    const int brow = (int)(g / BZ);

    const int tid  = threadIdx.x;
    const int wave = tid >> 6, lane = tid & 63;
    const int wm = (wave >> 1) * (MTILE / 2), wn = (wave & 1) * 64;
    const int lr = lane & 15, lq = lane >> 4;

    const char* Abc = (const char*)A + ((long)bz * sA + (size_t)brow * MTILE * K) * ES;
    const _Float16* Bb = Bm + (long)bz * sB + (size_t)col * 128 * K;

    f4_t acc[NI][4] = {};

    const char* gA[CHA];
    char* lA[CHA];
#pragma unroll
    for (int j = 0; j < CHA; ++j) {
        int c = tid + j * 256;
        int r = c / SEG, s = ((c & (SEG - 1)) - r) & (SEG - 1);
        gA[j] = Abc + ((size_t)r * K) * ES + s * 16;
        lA[j] = AsRaw + (size_t)c * 16;
    }
    const _Float16* gB[4];
    _Float16* lB[4];
#pragma unroll
    for (int j = 0; j < 4; ++j) {
        int c = tid + j * 256;
        int r = c >> 3, s = ((c & 7) - r) & 7;
        gB[j] = Bb + (size_t)r * K + s * 8;
        lB[j] = Bs + c * 8;
    }

    for (int kb = 0; kb < K; kb += 64) {
#pragma unroll
        for (int j = 0; j < CHA; ++j)
            __builtin_amdgcn_global_load_lds((void GLOBAL_AS*)(gA[j] + (size_t)kb * ES),
                                             (void LDS_AS*)lA[j], 16, 0, 0);
#pragma unroll
        for (int j = 0; j < 4; ++j)
            __builtin_amdgcn_global_load_lds((void GLOBAL_AS*)(gB[j] + kb), (void LDS_AS*)lB[j], 16, 0, 0);
        __syncthreads();

#pragma unroll
        for (int t = 0; t < 2; ++t) {
            h8 af[NI], bfr[4];
            if constexpr (AFP32) {
                const int s0 = t * 8 + lq * 2;   // 4-float seg index
#pragma unroll
                for (int i = 0; i < NI; ++i) {
                    int row = wm + i * 16 + lr;   // row & 15 == lr
                    f4_t a0 = *(const f4_t*)&As32[row * 64 + ((s0 + lr) & 15) * 4];
                    f4_t a1 = *(const f4_t*)&As32[row * 64 + ((s0 + 1 + lr) & 15) * 4];
#pragma unroll
                    for (int u = 0; u < 4; ++u) {
                        af[i][u] = (_Float16)a0[u];
                        af[i][4 + u] = (_Float16)a1[u];
                    }
                }
            } else {
                const int fs = ((t * 4 + lq + lr) & 7) * 8;   // row&7 == lr&7
#pragma unroll
                for (int i = 0; i < NI; ++i)
                    af[i] = *(const h8*)&As16[(wm + i * 16 + lr) * 64 + fs];
            }
            const int fsB = ((t * 4 + lq + lr) & 7) * 8;
#pragma unroll
            for (int j = 0; j < 4; ++j)
                bfr[j] = *(const h8*)&Bs[(wn + j * 16 + lr) * 64 + fsB];
#pragma unroll
            for (int i = 0; i < NI; ++i)
#pragma unroll
                for (int j = 0; j < 4; ++j)
                    acc[i][j] = __builtin_amdgcn_mfma_f32_16x16x32_f16(af[i], bfr[j], acc[i][j], 0, 0, 0);
        }
        __syncthreads();
    }

    const long row0 = (long)brow * MTILE + wm + lq * 4;
    const long col0 = (long)col * 128 + wn + lr;

    if constexpr (MODE == 3) {
        _Float16* C = (_Float16*)Cout + (long)bz * sC;
#pragma unroll
        for (int i = 0; i < NI; ++i)
#pragma unroll
            for (int j = 0; j < 4; ++j)
#pragma unroll
                for (int r = 0; r < 4; ++r) {
                    long row = row0 + i * 16 + r;
                    long ccol = col0 + j * 16;
                    bool keep = mask8[row * (long)N + ccol] != 0;
                    float v = acc[i][j][r] * scale;
                    v = fminf(fmaxf(v, -60000.0f), 60000.0f);
                    C[row * (long)N + ccol] = (_Float16)(keep ? v : -60000.0f);
                }
    } else {
        float bv[4];
        if constexpr (MODE != 0) {
            const void* bp = bias; const int* bfp = biasFlag; long boff = 0;
            if (bias2 != nullptr && col * 128 >= (N >> 1)) {
                bp = bias2; bfp = biasFlag2; boff = (long)(N >> 1);
            }
            const int bIs = *bfp;
#pragma unroll
            for (int j = 0; j < 4; ++j) bv[j] = rd(bp, col0 + j * 16 - boff, bIs);
        } else {
#pragma unroll
            for (int j = 0; j < 4; ++j) bv[j] = 0.0f;
        }
        if constexpr (MODE == 2) {
            float* C = (float*)Cout + (long)bz * sC;
#pragma unroll
            for (int i = 0; i < NI; ++i)
#pragma unroll
                for (int j = 0; j < 4; ++j)
#pragma unroll
                    for (int r = 0; r < 4; ++r)
                        C[(row0 + i * 16 + r) * (long)N + col0 + j * 16] = acc[i][j][r] + bv[j];
        } else {
            _Float16* C = (_Float16*)Cout + (long)bz * sC;
#pragma unroll
            for (int i = 0; i < NI; ++i)
#pragma unroll
                for (int j = 0; j < 4; ++j)
#pragma unroll
                    for (int r = 0; r < 4; ++r) {
                        float v = acc[i][j][r] + bv[j];
                        v = fminf(fmaxf(v, -65000.0f), 65000.0f);
                        C[(row0 + i * 16 + r) * (long)N + col0 + j * 16] = (_Float16)v;
                    }
        }
    }
}

// ---------------------------------------------------------------------------
struct ConvP {
    const _Float16* x; int xs; _Float16* y;
    const _Float16* kp; const _Float16* cb; const float* tg;
};
__global__ void k_dwconv2(ConvP p0, ConvP p1, int S, int D) {
    const ConvP& p = blockIdx.z ? p1 : p0;
    int s = blockIdx.x, b = blockIdx.y;
    int d0 = threadIdx.x * 8;
    const size_t xb = ((size_t)b * S + s) * p.xs + d0;
    const size_t yb = ((size_t)b * S + s) * D + d0;
    h8 zero;
#pragma unroll
    for (int u = 0; u < 8; ++u) zero[u] = (_Float16)0.0f;
    h8 xc = *(const h8*)(p.x + xb);
    h8 xp = (s > 0)     ? *(const h8*)(p.x + xb - p.xs) : zero;
    h8 xn = (s < S - 1) ? *(const h8*)(p.x + xb + p.xs) : zero;
    h8 k0 = *(const h8*)(p.kp + 0 * D + d0);
    h8 k1 = *(const h8*)(p.kp + 1 * D + d0);
    h8 k2 = *(const h8*)(p.kp + 2 * D + d0);
    h8 cb = *(const h8*)(p.cb + d0);
    float tg = *p.tg;
    h8 o;
#pragma unroll
    for (int u = 0; u < 8; ++u) {
        float cv = (float)xp[u] * (float)k0[u] + (float)xc[u] * (float)k1[u] +
                   (float)xn[u] * (float)k2[u] + (float)cb[u];
        float v = (float)xc[u] + tg * cv;
        o[u] = (_Float16)fminf(fmaxf(v, -65000.0f), 65000.0f);
    }
    *(h8*)(p.y + yb) = o;
}

// ---------------------------------------------------------------------------
__global__ void k_dwconv_t(const _Float16* __restrict__ x, int xs,
                           _Float16* __restrict__ vt,
                           const _Float16* __restrict__ kp,
                           const _Float16* __restrict__ cbp,
                           const float* __restrict__ tgp,
                           int SK, int D) {
    __shared__ _Float16 T[64][65];
    int b = blockIdx.z;
    int s0 = blockIdx.x * 64, d0 = blockIdx.y * 64;
    int tid = threadIdx.x;
    float tg = *tgp;
    h8 zero;
#pragma unroll
    for (int u = 0; u < 8; ++u) zero[u] = (_Float16)0.0f;
#pragma unroll
    for (int it = 0; it < 2; ++it) {
        int idx = it * 256 + tid;
        int r = idx >> 3, c = (idx & 7) * 8;
        int s = s0 + r;
        const size_t xb = ((size_t)b * SK + s) * xs + d0 + c;
        h8 xc = *(const h8*)(x + xb);
        h8 xp = (s > 0)      ? *(const h8*)(x + xb - xs) : zero;
        h8 xn = (s < SK - 1) ? *(const h8*)(x + xb + xs) : zero;
        h8 k0 = *(const h8*)(kp + 0 * D + d0 + c);
        h8 k1 = *(const h8*)(kp + 1 * D + d0 + c);
        h8 k2 = *(const h8*)(kp + 2 * D + d0 + c);
        h8 cb = *(const h8*)(cbp + d0 + c);
#pragma unroll
        for (int u = 0; u < 8; ++u) {
            float cv = (float)xp[u] * (float)k0[u] + (float)xc[u] * (float)k1[u] +
                       (float)xn[u] * (float)k2[u] + (float)cb[u];
            float v = (float)xc[u] + tg * cv;
            T[r][c + u] = (_Float16)fminf(fmaxf(v, -65000.0f), 65000.0f);
        }
    }
    __syncthreads();
#pragma unroll
    for (int it = 0; it < 2; ++it) {
        int idx = it * 256 + tid;
        int dr = idx >> 3, c = (idx & 7) * 8;
        h8 o;
#pragma unroll
        for (int u = 0; u < 8; ++u) o[u] = T[c + u][dr];
        *(h8*)(vt + ((size_t)b * D + d0 + dr) * SK + s0 + c) = o;
    }
}

// ---------------------------------------------------------------------------
__global__ __launch_bounds__(256) void k_softmax(const _Float16* __restrict__ sc,
                                                 _Float16* __restrict__ pr, int SK) {
    const long row = blockIdx.x;
    const int tid = threadIdx.x, lane = tid & 63, wave = tid >> 6;
    h8 v = *(const h8*)(sc + row * (long)SK + tid * 8);
    float f[8]; float mx = -3.0e38f;
#pragma unroll
    for (int u = 0; u < 8; ++u) { f[u] = (float)v[u]; mx = fmaxf(mx, f[u]); }
#pragma unroll
    for (int o = 32; o > 0; o >>= 1) mx = fmaxf(mx, __shfl_xor(mx, o, 64));
    __shared__ float red[8];
    if (lane == 0) red[wave] = mx;
    __syncthreads();
    mx = fmaxf(fmaxf(red[0], red[1]), fmaxf(red[2], red[3]));
    float sum = 0.0f;
#pragma unroll
    for (int u = 0; u < 8; ++u) { f[u] = __expf(f[u] - mx); sum += f[u]; }
#pragma unroll
    for (int o = 32; o > 0; o >>= 1) sum += __shfl_xor(sum, o, 64);
    if (lane == 0) red[4 + wave] = sum;
    __syncthreads();
    sum = red[4] + red[5] + red[6] + red[7];
    float inv = 1.0f / sum;
    h8 o8;
#pragma unroll
    for (int u = 0; u < 8; ++u) o8[u] = (_Float16)(f[u] * inv);
    *(h8*)(pr + row * (long)SK + tid * 8) = o8;
}

// ---------------------------------------------------------------------------
extern "C" void kernel_launch(void* const* d_in, const int* in_sizes, int n_in,
                              void* d_out, int out_size, void* d_ws, size_t ws_size,
                              hipStream_t stream) {
    const int Bn = 4, SQ = 2048, SK = 2048, D = 1024;
    const size_t nQ = (size_t)Bn * SQ * D;   // 8,388,608
    const long   nM = (long)SQ * SK;         // 4,194,304 mask elements

    const void* qh = d_in[0];
    const void* mh = d_in[1];
    const void* mask = d_in[2];
    const void* q_w = d_in[3];
    const void* q_b = d_in[4];
    const void* k_w = d_in[5];
    const void* k_b = d_in[6];
    const void* v_w = d_in[7];
    const void* v_b = d_in[8];
    const void* o_w = d_in[9];
    const void* o_b = d_in[10];
    const void* q_kern = d_in[11];
    const void* q_cb   = d_in[12];
    const void* q_g    = d_in[13];
    const void* k_kern = d_in[14];
    const void* k_cb   = d_in[15];
    const void* k_g    = d_in[16];
    const void* v_kern = d_in[17];
    const void* v_cb   = d_in[18];
    const void* v_g    = d_in[19];

    // ---- workspace layout (lifetime-overlaid) ----
    // [0,33.5MB)        scores -> attn_out
    // [33.5,41.9MB)     w16 x4 (q,k,v,o weights fp16) — live until out-proj;
    //                   par16/tgf overlay the TAIL 32KB of the o_w slot? NO —
    //                   par16 gets its own spot after flags.
    // [41.9,92.3MB)     lin_q + lin_kv; probs overlays after convs
    // [92.3,125.8MB)    conv_q, conv_k
    // [125.8,142.6MB)   vt  (must NOT alias lin_kv)
    // [142606336,+68B)  flags
    // [142610432,+4.2MB) mask8
    // [146804736,+24KB+12B) par16 + tgf
    char* ws = (char*)d_ws;
    _Float16* scores   = (_Float16*)(ws + 0);
    _Float16* attn_out = (_Float16*)(ws + 0);
    _Float16* w16      = (_Float16*)(ws + 33554432);
    _Float16* lin      = (_Float16*)(ws + 41943040);
    _Float16* lin_q    = lin;
    _Float16* lin_kv   = lin + nQ;
    _Float16* probs    = lin;
    _Float16* conv     = (_Float16*)(ws + 92274688);
    _Float16* vt       = (_Float16*)(ws + 125829120);
    int*      flags    = (int*)(ws + 142606336);
    unsigned char* mask8 = (unsigned char*)(ws + 142610432);
    _Float16* par16    = (_Float16*)(ws + 146804736);
    float*    tgf      = (float*)(ws + 146804736 + 12 * 1024 * 2);

    // 0. probes
    Probe16 pa;
    const void* pp[16] = {qh, mh, q_w, k_w, v_w, o_w, q_kern, k_kern, v_kern,
                          q_b, k_b, v_b, o_b, q_cb, k_cb, v_cb};
    const int   pn[16] = {2048, 2048, 2048, 2048, 2048, 2048, 3072, 3072, 3072,
                          1024, 1024, 1024, 1024, 1024, 1024, 1024};
    for (int i = 0; i < 16; ++i) { pa.p[i] = (const unsigned short*)pp[i]; pa.n[i] = pn[i]; }
    k_probes<<<17, 256, 0, stream>>>(pa, (const unsigned int*)mask, flags);

    // 1. merged prep: weight converts + mask pack + conv params
    const int nW8 = D * D / 8;
    Ptr4 wp; wp.p[0] = q_w; wp.p[1] = k_w; wp.p[2] = v_w; wp.p[3] = o_w;
    ConvSrc cs;
    cs.kern[0] = q_kern; cs.kern[1] = k_kern; cs.kern[2] = v_kern;
    cs.cb[0] = q_cb; cs.cb[1] = k_cb; cs.cb[2] = v_cb;
    cs.gate[0] = q_g; cs.gate[1] = k_g; cs.gate[2] = v_g;
    k_prep<<<6145, 256, 0, stream>>>(wp, w16, nW8, mask, mask8, nM, cs, par16, tgf, D, flags);

    // 2. projections, fp32 A direct (AFP32=1), MTILE=64
    k_gemm_nt<1, 64, 1><<<dim3(1024), 256, 0, stream>>>(
        qh, w16, lin_q, q_b, flags + 9, nullptr, nullptr,
        D, D, 0, 0, 0, 1.0f, nullptr, 8, 1);
    k_gemm_nt<1, 64, 1><<<dim3(2048), 256, 0, stream>>>(
        mh, w16 + (size_t)D * D, lin_kv, k_b, flags + 10, v_b, flags + 11,
        2 * D, D, 0, 0, 0, 1.0f, nullptr, 16, 1);

    // 3. gated depthwise conv: q + k one launch; v fused with transpose
    ConvP cq{lin_q, D, conv + 0 * nQ, par16 + 0 * 3 * D, par16 + 9 * D + 0 * D, tgf + 0};
    ConvP ck{lin_kv, 2 * D, conv + 1 * nQ, par16 + 1 * 3 * D, par16 + 9 * D + 1 * D, tgf + 1};
    k_dwconv2<<<dim3(SQ, Bn, 2), 128, 0, stream>>>(cq, ck, SQ, D);
    k_dwconv_t<<<dim3(SK / 64, D / 64, Bn), 256, 0, stream>>>(
        lin_kv + D, 2 * D, vt, par16 + 2 * 3 * D, par16 + 9 * D + 2 * D, tgf + 2, SK, D);

    // 5. scores: per-batch M=2048(128:16), N=2048 (NT=16), BZ=4 -> 1024 blocks
    k_gemm_nt<3, 128, 0><<<dim3(1024), 256, 0, stream>>>(
        conv + 0 * nQ, conv + 1 * nQ, scores, nullptr, nullptr, nullptr, nullptr,
        SK, D, (long)SQ * D, (long)SK * D, (long)SQ * SK, 0.03125f, mask8, 16, 4);

    // 6. softmax
    k_softmax<<<Bn * SQ, 256, 0, stream>>>(scores, probs, SK);

    // 7. attn @ v: per-batch M=2048(64:32), N=1024 (NT=8), BZ=4 -> 1024 blocks
    k_gemm_nt<0, 64, 0><<<dim3(1024), 256, 0, stream>>>(
        probs, vt, attn_out, nullptr, nullptr, nullptr, nullptr,
        D, SK, (long)SQ * SK, (long)D * SK, (long)SQ * D, 1.0f, nullptr, 8, 4);

    // 8. out-proj: M=8192(64:128), N=1024 (NT=8), BZ=1 -> 1024 blocks, fp32 out
    k_gemm_nt<2, 64, 0><<<dim3(1024), 256, 0, stream>>>(
        attn_out, w16 + 3 * (size_t)D * D, d_out, o_b, flags + 12, nullptr, nullptr,
        D, D, 0, 0, 0, 1.0f, nullptr, 8, 1);

    (void)in_sizes; (void)n_in; (void)out_size; (void)ws_size;
}